// Round 7
// baseline (289.416 us; speedup 1.0000x reference)
//
#include <hip/hip_runtime.h>
#include <math.h>

// Problem constants
#define T_DIM 1024
#define N_DIM 8192
#define M_TOT (T_DIM * N_DIM)      // 8,388,608
#define NVEC  (M_TOT / 4)          // 2,097,152 vec4 elements
#define NV4   (N_DIM / 4)          // 2048 vec4 per row
#define L_CHUNK 8
#define C_CHUNKS 128               // T_DIM / L_CHUNK

#define PC_BLOCKS  ((C_CHUNKS * NV4) / 256)    // 1024
#define MID_BLOCKS (N_DIM / 256)               // 32

#define kGAMMA 0.99f
#define kGLAM  (0.99f * 0.95f)

// ws layout (~20.07 MB):
//   [0, 256)        acc doubles: 0=mu, 1=inv(std+1e-5)
//   +256            pm  [32][2]  doubles (512 B)   -- k_mid partials
//   +1024           pl  [1024][3] doubles (24 KB)  -- k_big partials
//   +65536          b16 [T][N] ushort (16 MB)
//   +65536+16MB     g_in [C][N] float (4 MB)

__device__ __forceinline__ unsigned short f2bf(float f) {
    unsigned int u = __float_as_uint(f);
    u += 0x7fffu + ((u >> 16) & 1u);        // round-to-nearest-even
    return (unsigned short)(u >> 16);
}
__device__ __forceinline__ float bf2f(unsigned short h) {
    return __uint_as_float(((unsigned int)h) << 16);
}

// ---------------------------------------------------------------------------
// P1: streaming prep. Thread (c, j): row-serial descending-t loop with vnext
// carry; computes b_t = (r + g*m*vnext - v)*bb, stored bf16 with the a-bit
// (m*bb != 0) packed into the LSB (a-decode is then exact; b loses <=1 ulp).
__global__ __launch_bounds__(256) void k_pc(
    const float4* __restrict__ r4,
    const float4* __restrict__ m4,     // (T+1) rows
    const float4* __restrict__ bm4,    // (T+1) rows
    const float4* __restrict__ vp4,    // (T+1) rows
    const float4* __restrict__ lv4,    // (N,)
    ushort4* __restrict__ b16)
{
    const int g  = blockIdx.x * 256 + threadIdx.x;   // 0 .. C*NV4-1
    const int j  = g & (NV4 - 1);
    const int c  = g >> 11;
    const int t0 = c * L_CHUNK;

    float4 vnext = (c == C_CHUNKS - 1) ? lv4[j] : vp4[(t0 + L_CHUNK) * NV4 + j];

    #pragma unroll
    for (int i = L_CHUNK - 1; i >= 0; --i) {
        const int idx = (t0 + i) * NV4 + j;
        const float4 r  = r4[idx];
        const float4 v  = vp4[idx];
        const float4 m  = m4[idx + NV4];             // row t+1
        const float4 bb = bm4[idx + NV4];            // row t+1

        ushort4 o;
        {
            const float b = (fmaf(kGAMMA * m.x, vnext.x, r.x) - v.x) * bb.x;
            o.x = (unsigned short)((f2bf(b) & 0xFFFEu) | ((m.x * bb.x > 0.5f) ? 1u : 0u));
        }
        {
            const float b = (fmaf(kGAMMA * m.y, vnext.y, r.y) - v.y) * bb.y;
            o.y = (unsigned short)((f2bf(b) & 0xFFFEu) | ((m.y * bb.y > 0.5f) ? 1u : 0u));
        }
        {
            const float b = (fmaf(kGAMMA * m.z, vnext.z, r.z) - v.z) * bb.z;
            o.z = (unsigned short)((f2bf(b) & 0xFFFEu) | ((m.z * bb.z > 0.5f) ? 1u : 0u));
        }
        {
            const float b = (fmaf(kGAMMA * m.w, vnext.w, r.w) - v.w) * bb.w;
            o.w = (unsigned short)((f2bf(b) & 0xFFFEu) | ((m.w * bb.w > 0.5f) ? 1u : 0u));
        }
        b16[idx] = o;
        vnext = v;
    }
}

// ---------------------------------------------------------------------------
// P2: per-env serial scan over ALL of b16 (L2/L3-resident, 2 B/elt).
// Computes exact running gae, global sum g / sum g^2 (block partials via
// plain stores), and writes each chunk's entry value g_in[c][n].
__global__ __launch_bounds__(256) void k_mid(
    const unsigned short* __restrict__ b16,
    float* __restrict__ g_in,          // [C][N]
    double* __restrict__ pm)           // [MID_BLOCKS][2]
{
    const int n = blockIdx.x * 256 + threadIdx.x;   // 0..N-1
    float g = 0.f, sg = 0.f, sg2 = 0.f;

    constexpr int PB = 32;
    for (int tb = T_DIM - PB; tb >= 0; tb -= PB) {
        unsigned short h[PB];
        #pragma unroll
        for (int i = 0; i < PB; ++i) h[i] = b16[(tb + i) * N_DIM + n];
        #pragma unroll
        for (int i = PB - 1; i >= 0; --i) {
            const int t = tb + i;
            if ((t & (L_CHUNK - 1)) == (L_CHUNK - 1)) {
                g_in[(t >> 3) * N_DIM + n] = g;     // entry value for chunk t>>3
            }
            const float bf = bf2f(h[i]);
            const float a  = (h[i] & 1u) ? kGLAM : 0.0f;
            g = fmaf(a, g, bf);
            sg += g;
            sg2 = fmaf(g, g, sg2);
        }
    }

    double d0 = (double)sg, d1 = (double)sg2;
    #pragma unroll
    for (int off = 32; off > 0; off >>= 1) {
        d0 += __shfl_down(d0, off, 64);
        d1 += __shfl_down(d1, off, 64);
    }
    __shared__ double sh[2][4];
    const int wid = threadIdx.x >> 6, lane = threadIdx.x & 63;
    if (lane == 0) { sh[0][wid] = d0; sh[1][wid] = d1; }
    __syncthreads();
    if (threadIdx.x == 0) {
        double t0s = 0, t1s = 0;
        #pragma unroll
        for (int w = 0; w < 4; ++w) { t0s += sh[0][w]; t1s += sh[1][w]; }
        pm[blockIdx.x * 2 + 0] = t0s;   // plain stores, zero contention
        pm[blockIdx.x * 2 + 1] = t1s;
    }
}

// ---------------------------------------------------------------------------
// P3: finalize mu / inv(std+eps) from k_mid partials. One block.
__global__ __launch_bounds__(64) void k_stats(
    const double* __restrict__ pm, double* __restrict__ acc)
{
    double s0 = 0.0, s1 = 0.0;
    if (threadIdx.x < MID_BLOCKS) {
        s0 = pm[threadIdx.x * 2 + 0];
        s1 = pm[threadIdx.x * 2 + 1];
    }
    #pragma unroll
    for (int off = 32; off > 0; off >>= 1) {
        s0 += __shfl_down(s0, off, 64);
        s1 += __shfl_down(s1, off, 64);
    }
    if (threadIdx.x == 0) {
        const double M = (double)M_TOT;
        const double mu = s0 / M;
        double var = (s1 - s0 * s0 / M) / (M - 1.0);
        if (var < 0.0) var = 0.0;
        acc[0] = mu;
        acc[1] = 1.0 / (sqrt(var) + 1e-5);
    }
}

// ---------------------------------------------------------------------------
// P4: THE fused loss pass. Thread (c, j): recompute gae from b16 + g_in,
// value loss + action loss + entropy in one 180 MB sweep. Partials -> pl.
__global__ __launch_bounds__(256) void k_big(
    const ushort4* __restrict__ b16,
    const float4* __restrict__ g_in4,  // [C][NV4]
    const float4* __restrict__ vp4,
    const float4* __restrict__ nv4,
    const float4* __restrict__ lp4,
    const float4* __restrict__ plp4,
    const float4* __restrict__ ent4,
    const double* __restrict__ acc,
    double* __restrict__ pl)           // [PC_BLOCKS][3]
{
    const int g  = blockIdx.x * 256 + threadIdx.x;   // 0 .. C*NV4-1
    const int j  = g & (NV4 - 1);
    const int c  = g >> 11;
    const int t0 = c * L_CHUNK;

    const float mu   = (float)acc[0];
    const float invs = (float)acc[1];

    float4 gae = g_in4[c * NV4 + j];
    float a_s = 0.f, v_s = 0.f, e_s = 0.f;

    #pragma unroll
    for (int i = L_CHUNK - 1; i >= 0; --i) {
        const int idx = (t0 + i) * NV4 + j;
        const ushort4 h = b16[idx];
        const float4  v = vp4[idx];
        const float4  q = nv4[idx];
        const float4  L = lp4[idx];
        const float4  P = plp4[idx];
        const float4  E = ent4[idx];

        const unsigned short hh[4] = {h.x, h.y, h.z, h.w};
        const float vs[4] = {v.x, v.y, v.z, v.w};
        const float qs[4] = {q.x, q.y, q.z, q.w};
        const float ls[4] = {L.x, L.y, L.z, L.w};
        const float ps[4] = {P.x, P.y, P.z, P.w};
        float gg[4] = {gae.x, gae.y, gae.z, gae.w};

        #pragma unroll
        for (int u = 0; u < 4; ++u) {
            const float bf = bf2f(hh[u]);
            const float a  = (hh[u] & 1u) ? kGLAM : 0.0f;
            gg[u] = fmaf(a, gg[u], bf);
            // value loss
            const float d  = qs[u] - vs[u];
            const float e1 = d - gg[u];
            const float e2 = fminf(fmaxf(d, -0.2f), 0.2f) - gg[u];
            v_s += fmaxf(e1 * e1, e2 * e2);
            // action loss
            const float x  = (gg[u] - mu) * invs;
            const float r  = __expf(ls[u] - ps[u]);
            const float rc = fminf(fmaxf(r, 0.8f), 1.2f);
            a_s += fminf(r * x, rc * x);
        }
        e_s += E.x + E.y + E.z + E.w;
        gae.x = gg[0]; gae.y = gg[1]; gae.z = gg[2]; gae.w = gg[3];
    }

    double d0 = (double)a_s, d1 = (double)v_s, d2 = (double)e_s;
    #pragma unroll
    for (int off = 32; off > 0; off >>= 1) {
        d0 += __shfl_down(d0, off, 64);
        d1 += __shfl_down(d1, off, 64);
        d2 += __shfl_down(d2, off, 64);
    }
    __shared__ double sh[3][4];
    const int wid = threadIdx.x >> 6, lane = threadIdx.x & 63;
    if (lane == 0) { sh[0][wid] = d0; sh[1][wid] = d1; sh[2][wid] = d2; }
    __syncthreads();
    if (threadIdx.x == 0) {
        double t0s = 0, t1s = 0, t2s = 0;
        #pragma unroll
        for (int w = 0; w < 4; ++w) { t0s += sh[0][w]; t1s += sh[1][w]; t2s += sh[2][w]; }
        pl[blockIdx.x * 3 + 0] = t0s;
        pl[blockIdx.x * 3 + 1] = t1s;
        pl[blockIdx.x * 3 + 2] = t2s;
    }
}

// ---------------------------------------------------------------------------
// P5: reduce k_big partials -> final scalar loss. One block.
__global__ __launch_bounds__(256) void k_final(
    const double* __restrict__ pl, float* __restrict__ out)
{
    double s0 = 0.0, s1 = 0.0, s2 = 0.0;
    for (int i = threadIdx.x; i < PC_BLOCKS; i += 256) {
        s0 += pl[i * 3 + 0];
        s1 += pl[i * 3 + 1];
        s2 += pl[i * 3 + 2];
    }
    #pragma unroll
    for (int off = 32; off > 0; off >>= 1) {
        s0 += __shfl_down(s0, off, 64);
        s1 += __shfl_down(s1, off, 64);
        s2 += __shfl_down(s2, off, 64);
    }
    __shared__ double sh[3][4];
    const int wid = threadIdx.x >> 6, lane = threadIdx.x & 63;
    if (lane == 0) { sh[0][wid] = s0; sh[1][wid] = s1; sh[2][wid] = s2; }
    __syncthreads();
    if (threadIdx.x == 0) {
        double a_sum = 0, v_sum = 0, e_sum = 0;
        #pragma unroll
        for (int w = 0; w < 4; ++w) { a_sum += sh[0][w]; v_sum += sh[1][w]; e_sum += sh[2][w]; }
        const double M = (double)M_TOT;
        out[0] = (float)(0.25 * v_sum / M - a_sum / M - 0.01 * e_sum / M);
    }
}

// ---------------------------------------------------------------------------
extern "C" void kernel_launch(void* const* d_in, const int* in_sizes, int n_in,
                              void* d_out, int out_size, void* d_ws, size_t ws_size,
                              hipStream_t stream) {
    const float* rewards     = (const float*)d_in[0];   // (T, N)
    const float* masks       = (const float*)d_in[1];   // (T+1, N)
    const float* bad_masks   = (const float*)d_in[2];   // (T+1, N)
    const float* value_preds = (const float*)d_in[3];   // (T+1, N)
    const float* last_value  = (const float*)d_in[4];   // (N,)
    const float* log_prob    = (const float*)d_in[5];   // (T, N)
    const float* prev_lp     = (const float*)d_in[6];   // (T, N)
    const float* new_value   = (const float*)d_in[7];   // (T, N)
    const float* dist_ent    = (const float*)d_in[8];   // (T, N)

    char* ws = (char*)d_ws;
    double* acc = (double*)ws;
    double* pm  = (double*)(ws + 256);
    double* pl  = (double*)(ws + 1024);
    unsigned short* b16 = (unsigned short*)(ws + 65536);
    float* g_in = (float*)(ws + 65536 + (size_t)M_TOT * 2);

    k_pc<<<PC_BLOCKS, 256, 0, stream>>>((const float4*)rewards,
                                        (const float4*)masks,
                                        (const float4*)bad_masks,
                                        (const float4*)value_preds,
                                        (const float4*)last_value,
                                        (ushort4*)b16);
    k_mid<<<MID_BLOCKS, 256, 0, stream>>>(b16, g_in, pm);
    k_stats<<<1, 64, 0, stream>>>(pm, acc);
    k_big<<<PC_BLOCKS, 256, 0, stream>>>((const ushort4*)b16,
                                         (const float4*)g_in,
                                         (const float4*)value_preds,
                                         (const float4*)new_value,
                                         (const float4*)log_prob,
                                         (const float4*)prev_lp,
                                         (const float4*)dist_ent,
                                         acc, pl);
    k_final<<<1, 256, 0, stream>>>(pl, (float*)d_out);
}